// Round 3
// baseline (984.827 us; speedup 1.0000x reference)
//
#include <hip/hip_runtime.h>
#include <hip/hip_bf16.h>
#include <math.h>

#define T_TOK 8192
#define HDIM  1024
#define IDIM  4096
#define SDIM  128
#define TOPK  16

typedef __bf16 bf16x8 __attribute__((ext_vector_type(8)));
typedef float  f32x4  __attribute__((ext_vector_type(4)));

__device__ __forceinline__ unsigned short f2bf(float f) {
    union { float f; unsigned u; } a; a.f = f;
    unsigned r = a.u + 0x7fffu + ((a.u >> 16) & 1u);
    return (unsigned short)(r >> 16);
}
__device__ __forceinline__ float bf2f(unsigned short b) {
    union { unsigned u; float f; } a; a.u = ((unsigned)b) << 16;
    return a.f;
}

__device__ __forceinline__ void gld_lds16(const void* g, void* l) {
    __builtin_amdgcn_global_load_lds(
        (__attribute__((address_space(1))) void*)g,
        (__attribute__((address_space(3))) void*)l,
        16, 0, 0);
}

// ---------------- merged fp32 -> bf16 convert over 8 segments ----------------
struct CvtSegs {
    const float4* src[8];
    ushort4*      dst[8];
    int           end[8];   // prefix-sum of float4 counts
};

__global__ __launch_bounds__(256)
void cvt_all_kernel(CvtSegs segs) {
    int i = blockIdx.x * 256 + threadIdx.x;
    if (i >= segs.end[7]) return;
    int s = 0;
    #pragma unroll
    for (int k = 0; k < 7; ++k) s += (i >= segs.end[k]) ? 1 : 0;
    int base = (s == 0) ? 0 : segs.end[s - 1];
    int j = i - base;
    float4 v = segs.src[s][j];
    ushort4 o;
    o.x = f2bf(v.x); o.y = f2bf(v.y); o.z = f2bf(v.z); o.w = f2bf(v.w);
    segs.dst[s][j] = o;
}

// ---------------- generic C = A * B^T (bf16 in, fp32 out), 128x128 tile ----------------
template<int ADD>
__global__ __launch_bounds__(256)
void gemm_bt(const unsigned short* __restrict__ A, const unsigned short* __restrict__ B,
             float* __restrict__ C, int M, int N, int K) {
    __shared__ unsigned short As[4096];  // [kc=4][m=128][8] bf16
    __shared__ unsigned short Bs[4096];  // [kc=4][n=128][8]
    const int tid  = threadIdx.x;
    const int lane = tid & 63;
    const int wave = tid >> 6;
    const int tm = blockIdx.x * 128;
    const int tn = blockIdx.y * 128;
    const int wm = (wave & 1) * 64;
    const int wn = (wave >> 1) * 64;
    const int quad = lane >> 4;
    const int tr   = lane & 15;

    f32x4 acc[4][4] = {};

    const int ua0 = tid,        am0 = ua0 & 127, ak0 = ua0 >> 7;
    const int ua1 = tid + 256,  am1 = ua1 & 127, ak1 = ua1 >> 7;

    for (int kt = 0; kt < K; kt += 32) {
        __syncthreads();
        gld_lds16(A + (size_t)(tm + am0) * K + kt + ak0 * 8, &As[ua0 * 8]);
        gld_lds16(A + (size_t)(tm + am1) * K + kt + ak1 * 8, &As[ua1 * 8]);
        gld_lds16(B + (size_t)(tn + am0) * K + kt + ak0 * 8, &Bs[ua0 * 8]);
        gld_lds16(B + (size_t)(tn + am1) * K + kt + ak1 * 8, &Bs[ua1 * 8]);
        asm volatile("s_waitcnt vmcnt(0)" ::: "memory");
        __syncthreads();
        bf16x8 af[4], bfr[4];
        #pragma unroll
        for (int mi = 0; mi < 4; ++mi)
            af[mi] = *(const bf16x8*)&As[(quad * 128 + wm + mi * 16 + tr) * 8];
        #pragma unroll
        for (int ni = 0; ni < 4; ++ni)
            bfr[ni] = *(const bf16x8*)&Bs[(quad * 128 + wn + ni * 16 + tr) * 8];
        #pragma unroll
        for (int mi = 0; mi < 4; ++mi)
            #pragma unroll
            for (int ni = 0; ni < 4; ++ni)
                acc[mi][ni] = __builtin_amdgcn_mfma_f32_16x16x32_bf16(af[mi], bfr[ni], acc[mi][ni], 0, 0, 0);
    }
    #pragma unroll
    for (int mi = 0; mi < 4; ++mi) {
        #pragma unroll
        for (int ni = 0; ni < 4; ++ni) {
            int col = tn + wn + ni * 16 + tr;
            #pragma unroll
            for (int r = 0; r < 4; ++r) {
                int row = tm + wm + mi * 16 + quad * 4 + r;
                size_t o = (size_t)row * N + col;
                float v = acc[mi][ni][r];
                if (ADD) v += C[o];
                C[o] = v;
            }
        }
    }
}

// ---------------- fused GEMM1: h = silu(x @ Wg^T) * (x @ Wu^T), bf16 out ----------------
// tile 128(M) x 128(N), dual-B, BK=32: 32 MFMAs per barrier-pair per wave
__global__ __launch_bounds__(256)
void gemm1_swiglu(const unsigned short* __restrict__ Xb, const unsigned short* __restrict__ Wg,
                  const unsigned short* __restrict__ Wu, unsigned short* __restrict__ Hb) {
    const int K = HDIM, N = IDIM;
    __shared__ unsigned short As[4096];  // [kc=4][128][8] 8KB
    __shared__ unsigned short Bg[4096];
    __shared__ unsigned short Bu[4096];
    const int tid  = threadIdx.x;
    const int lane = tid & 63;
    const int wave = tid >> 6;
    const int tm = blockIdx.x * 128;
    const int tn = blockIdx.y * 128;
    const int wm = (wave & 1) * 64;
    const int wn = (wave >> 1) * 64;
    const int quad = lane >> 4;
    const int tr   = lane & 15;

    f32x4 ag[4][4] = {};
    f32x4 au[4][4] = {};

    const int ua0 = tid,        am0 = ua0 & 127, ak0 = ua0 >> 7;
    const int ua1 = tid + 256,  am1 = ua1 & 127, ak1 = ua1 >> 7;

    for (int kt = 0; kt < K; kt += 32) {
        __syncthreads();
        gld_lds16(Xb + (size_t)(tm + am0) * K + kt + ak0 * 8, &As[ua0 * 8]);
        gld_lds16(Xb + (size_t)(tm + am1) * K + kt + ak1 * 8, &As[ua1 * 8]);
        gld_lds16(Wg + (size_t)(tn + am0) * K + kt + ak0 * 8, &Bg[ua0 * 8]);
        gld_lds16(Wg + (size_t)(tn + am1) * K + kt + ak1 * 8, &Bg[ua1 * 8]);
        gld_lds16(Wu + (size_t)(tn + am0) * K + kt + ak0 * 8, &Bu[ua0 * 8]);
        gld_lds16(Wu + (size_t)(tn + am1) * K + kt + ak1 * 8, &Bu[ua1 * 8]);
        asm volatile("s_waitcnt vmcnt(0)" ::: "memory");
        __syncthreads();
        bf16x8 af[4], bg[4], bu[4];
        #pragma unroll
        for (int mi = 0; mi < 4; ++mi)
            af[mi] = *(const bf16x8*)&As[(quad * 128 + wm + mi * 16 + tr) * 8];
        #pragma unroll
        for (int ni = 0; ni < 4; ++ni) {
            bg[ni] = *(const bf16x8*)&Bg[(quad * 128 + wn + ni * 16 + tr) * 8];
            bu[ni] = *(const bf16x8*)&Bu[(quad * 128 + wn + ni * 16 + tr) * 8];
        }
        #pragma unroll
        for (int mi = 0; mi < 4; ++mi)
            #pragma unroll
            for (int ni = 0; ni < 4; ++ni) {
                ag[mi][ni] = __builtin_amdgcn_mfma_f32_16x16x32_bf16(af[mi], bg[ni], ag[mi][ni], 0, 0, 0);
                au[mi][ni] = __builtin_amdgcn_mfma_f32_16x16x32_bf16(af[mi], bu[ni], au[mi][ni], 0, 0, 0);
            }
    }
    #pragma unroll
    for (int mi = 0; mi < 4; ++mi) {
        #pragma unroll
        for (int ni = 0; ni < 4; ++ni) {
            int col = tn + wn + ni * 16 + tr;
            #pragma unroll
            for (int r = 0; r < 4; ++r) {
                int row = tm + wm + mi * 16 + quad * 4 + r;
                float g = ag[mi][ni][r];
                float u = au[mi][ni][r];
                float h = g / (1.0f + __expf(-g)) * u;  // silu(g)*u
                Hb[(size_t)row * N + col] = f2bf(h);
            }
        }
    }
}

// ---------------- batchnorm stats ----------------
__global__ void bn_stats(const float* __restrict__ gxy, float* __restrict__ sums, float* __restrict__ ssq) {
    const int j = threadIdx.x;
    const int b = blockIdx.x;
    float s = 0.f, q = 0.f;
    for (int r = 0; r < 32; ++r) {
        float v = gxy[(size_t)(b * 32 + r) * 256 + j];
        s += v; q += v * v;
    }
    atomicAdd(&sums[j], s);
    atomicAdd(&ssq[j], q);
}

// ---------------- routing: bn -> log_softmax -> top16 via candidate reduction ----------------
__global__ __launch_bounds__(256)
void routing_kernel(const float* __restrict__ gxy, const float* __restrict__ sums,
                    const float* __restrict__ ssq, int* __restrict__ oidx, float* __restrict__ owt) {
    const int lane = threadIdx.x & 63;
    const int t = blockIdx.x * 4 + (threadIdx.x >> 6);
    const float invT = 1.0f / (float)T_TOK;
    const float* g = gxy + (size_t)t * 256;

    float z[4];
    const int cols[4] = {lane, lane + 64, 128 + lane, 192 + lane};
    #pragma unroll
    for (int i = 0; i < 4; ++i) {
        int c = cols[i];
        float mu  = sums[c] * invT;
        float var = ssq[c] * invT - mu * mu;
        z[i] = (g[c] - mu) * rsqrtf(var + 1e-5f);
    }
    float mx = fmaxf(z[0], z[1]);
    float my = fmaxf(z[2], z[3]);
    #pragma unroll
    for (int m = 32; m >= 1; m >>= 1) {
        mx = fmaxf(mx, __shfl_xor(mx, m));
        my = fmaxf(my, __shfl_xor(my, m));
    }
    float sx = __expf(z[0] - mx) + __expf(z[1] - mx);
    float sy = __expf(z[2] - my) + __expf(z[3] - my);
    #pragma unroll
    for (int m = 32; m >= 1; m >>= 1) {
        sx += __shfl_xor(sx, m);
        sy += __shfl_xor(sy, m);
    }
    float lx0 = z[0] - (mx + __logf(sx)), lx1 = z[1] - (mx + __logf(sx));
    float ly0 = z[2] - (my + __logf(sy)), ly1 = z[3] - (my + __logf(sy));

    float aw = -INFINITY; int ai = 0;
    float bw = -INFINITY; int bi = 0;
    {
        float v0 = lx0, v1 = lx1;
        for (int i = 0; i < 16; ++i) {
            float v; int c;
            if (v0 >= v1) { v = v0; c = lane; } else { v = v1; c = lane + 64; }
            #pragma unroll
            for (int m = 32; m >= 1; m >>= 1) {
                float ov = __shfl_xor(v, m); int oc = __shfl_xor(c, m);
                if (ov > v || (ov == v && oc < c)) { v = ov; c = oc; }
            }
            if ((c & 63) == lane) { if (c < 64) v0 = -INFINITY; else v1 = -INFINITY; }
            if (lane == i) { aw = v; ai = c; }
        }
    }
    {
        float v0 = ly0, v1 = ly1;
        for (int i = 0; i < 16; ++i) {
            float v; int c;
            if (v0 >= v1) { v = v0; c = lane; } else { v = v1; c = lane + 64; }
            #pragma unroll
            for (int m = 32; m >= 1; m >>= 1) {
                float ov = __shfl_xor(v, m); int oc = __shfl_xor(c, m);
                if (ov > v || (ov == v && oc < c)) { v = ov; c = oc; }
            }
            if ((c & 63) == lane) { if (c < 64) v0 = -INFINITY; else v1 = -INFINITY; }
            if (lane == i) { bw = v; bi = c; }
        }
    }
    float cv[4];
    #pragma unroll
    for (int j = 0; j < 4; ++j) {
        int c = lane + 64 * j;
        cv[j] = __shfl(aw, c >> 4) + __shfl(bw, c & 15);
    }
    int myidx = 0; float myw = 0.f;
    for (int i = 0; i < 16; ++i) {
        float v = cv[0]; int c = lane;
        #pragma unroll
        for (int j = 1; j < 4; ++j) { int cc = lane + 64 * j; if (cv[j] > v) { v = cv[j]; c = cc; } }
        #pragma unroll
        for (int m = 32; m >= 1; m >>= 1) {
            float ov = __shfl_xor(v, m); int oc = __shfl_xor(c, m);
            if (ov > v || (ov == v && oc < c)) { v = ov; c = oc; }
        }
        #pragma unroll
        for (int j = 0; j < 4; ++j) if (c == lane + 64 * j) cv[j] = -INFINITY;
        int p = c >> 4, q = c & 15;
        int ex = __shfl(ai, p);
        int ey = __shfl(bi, q);
        if (lane == i) { myidx = ex * 128 + ey; myw = __expf(v); }
    }
    if (lane < 16) {
        oidx[t * TOPK + lane] = myidx;
        owt[t * TOPK + lane]  = myw;
    }
}

// ---------------- expert gather/combine (bf16 tables + bf16 x) ----------------
__global__ __launch_bounds__(256)
void expert_combine(const unsigned short* __restrict__ xb, const int* __restrict__ idx,
                    const float* __restrict__ wts, const unsigned short* __restrict__ ueb,
                    const unsigned short* __restrict__ deb, float* __restrict__ out) {
    const int t = blockIdx.x;
    const int tid = threadIdx.x;
    const int lane = tid & 63, wv = tid >> 6;
    __shared__ float part[TOPK * 4];
    __shared__ float sc[TOPK];
    ushort4 xv4 = ((const ushort4*)(xb + (size_t)t * HDIM))[tid];
    float x0 = bf2f(xv4.x), x1 = bf2f(xv4.y), x2 = bf2f(xv4.z), x3 = bf2f(xv4.w);
    int e[TOPK];
    #pragma unroll
    for (int k = 0; k < TOPK; ++k) e[k] = idx[t * TOPK + k];
    #pragma unroll
    for (int k = 0; k < TOPK; ++k) {
        ushort4 u4 = ((const ushort4*)(ueb + (size_t)e[k] * HDIM))[tid];
        float p = bf2f(u4.x) * x0 + bf2f(u4.y) * x1 + bf2f(u4.z) * x2 + bf2f(u4.w) * x3;
        #pragma unroll
        for (int m = 32; m >= 1; m >>= 1) p += __shfl_xor(p, m);
        if (lane == 0) part[k * 4 + wv] = p;
    }
    __syncthreads();
    if (tid < TOPK) {
        float s = part[tid * 4] + part[tid * 4 + 1] + part[tid * 4 + 2] + part[tid * 4 + 3];
        sc[tid] = s * wts[t * TOPK + tid];
    }
    __syncthreads();
    float4 acc = {0.f, 0.f, 0.f, 0.f};
    #pragma unroll
    for (int k = 0; k < TOPK; ++k) {
        float s = sc[k];
        ushort4 d4 = ((const ushort4*)(deb + (size_t)e[k] * HDIM))[tid];
        acc.x += s * bf2f(d4.x); acc.y += s * bf2f(d4.y);
        acc.z += s * bf2f(d4.z); acc.w += s * bf2f(d4.w);
    }
    ((float4*)(out + (size_t)t * HDIM))[tid] = acc;
}

extern "C" void kernel_launch(void* const* d_in, const int* in_sizes, int n_in,
                              void* d_out, int out_size, void* d_ws, size_t ws_size,
                              hipStream_t stream) {
    const float* x  = (const float*)d_in[0];
    const float* gw = (const float*)d_in[1];
    const float* uw = (const float*)d_in[2];
    const float* dw = (const float*)d_in[3];
    const float* wx = (const float*)d_in[4];
    const float* wy = (const float*)d_in[5];
    const float* ue = (const float*)d_in[6];
    const float* de = (const float*)d_in[7];
    float* out = (float*)d_out;

    char* ws = (char*)d_ws;
    size_t o = 0;
    auto alloc = [&](size_t bytes) { void* p = ws + o; o += (bytes + 255) & ~(size_t)255; return p; };
    unsigned short* xb    = (unsigned short*)alloc((size_t)T_TOK * HDIM * 2);
    unsigned short* gateb = (unsigned short*)alloc((size_t)IDIM * HDIM * 2);
    unsigned short* upb   = (unsigned short*)alloc((size_t)IDIM * HDIM * 2);
    unsigned short* downb = (unsigned short*)alloc((size_t)HDIM * IDIM * 2);
    unsigned short* wrb   = (unsigned short*)alloc((size_t)256 * HDIM * 2);
    unsigned short* ueb   = (unsigned short*)alloc((size_t)16384 * HDIM * 2);
    unsigned short* deb   = (unsigned short*)alloc((size_t)16384 * HDIM * 2);
    unsigned short* hbuf  = (unsigned short*)alloc((size_t)T_TOK * IDIM * 2);
    float* gxy  = (float*)alloc((size_t)T_TOK * 256 * 4);
    float* sums = (float*)alloc(256 * 4);
    float* ssq  = (float*)alloc(256 * 4);
    int*   idxs = (int*)alloc((size_t)T_TOK * TOPK * 4);
    float* wts  = (float*)alloc((size_t)T_TOK * TOPK * 4);

    // merged converts (8 segments)
    CvtSegs segs;
    const float* srcs[8] = {x, gw, uw, dw, wx, wy, ue, de};
    unsigned short* dsts[8] = {xb, gateb, upb, downb, wrb, wrb + SDIM * HDIM, ueb, deb};
    const int cnt4[8] = {T_TOK * HDIM / 4, IDIM * HDIM / 4, IDIM * HDIM / 4, IDIM * HDIM / 4,
                         SDIM * HDIM / 4, SDIM * HDIM / 4, 16384 * HDIM / 4, 16384 * HDIM / 4};
    int acc = 0;
    for (int i = 0; i < 8; ++i) {
        segs.src[i] = (const float4*)srcs[i];
        segs.dst[i] = (ushort4*)dsts[i];
        acc += cnt4[i];
        segs.end[i] = acc;
    }
    cvt_all_kernel<<<(acc + 255) / 256, 256, 0, stream>>>(segs);

    // router logits: gxy[T,256] = xb @ wrb^T
    hipMemsetAsync(sums, 0, 2 * 256 * 4, stream);  // sums+ssq contiguous
    gemm_bt<0><<<dim3(T_TOK / 128, 256 / 128), 256, 0, stream>>>(xb, wrb, gxy, T_TOK, 256, HDIM);
    bn_stats<<<256, 256, 0, stream>>>(gxy, sums, ssq);
    routing_kernel<<<T_TOK / 4, 256, 0, stream>>>(gxy, sums, ssq, idxs, wts);

    // expert branch writes out fully
    expert_combine<<<T_TOK, 256, 0, stream>>>(xb, idxs, wts, ueb, deb, out);

    // MLP branch
    gemm1_swiglu<<<dim3(T_TOK / 128, IDIM / 128), 256, 0, stream>>>(xb, gateb, upb, hbuf);
    gemm_bt<1><<<dim3(T_TOK / 128, HDIM / 128), 256, 0, stream>>>(hbuf, downb, out, T_TOK, HDIM, IDIM);
}

// Round 4
// 856.690 us; speedup vs baseline: 1.1496x; 1.1496x over previous
//
#include <hip/hip_runtime.h>
#include <hip/hip_bf16.h>
#include <math.h>

#define T_TOK 8192
#define HDIM  1024
#define IDIM  4096
#define SDIM  128
#define TOPK  16

typedef __bf16 bf16x8 __attribute__((ext_vector_type(8)));
typedef float  f32x4  __attribute__((ext_vector_type(4)));

__device__ __forceinline__ unsigned short f2bf(float f) {
    union { float f; unsigned u; } a; a.f = f;
    unsigned r = a.u + 0x7fffu + ((a.u >> 16) & 1u);
    return (unsigned short)(r >> 16);
}
__device__ __forceinline__ float bf2f(unsigned short b) {
    union { unsigned u; float f; } a; a.u = ((unsigned)b) << 16;
    return a.f;
}

__device__ __forceinline__ void gld_lds16(const void* g, void* l) {
    __builtin_amdgcn_global_load_lds(
        (__attribute__((address_space(1))) void*)g,
        (__attribute__((address_space(3))) void*)l,
        16, 0, 0);
}

// ---------------- merged fp32 -> bf16 convert over 8 segments ----------------
struct CvtSegs {
    const float4* src[8];
    ushort4*      dst[8];
    int           end[8];   // prefix-sum of float4 counts
};

__global__ __launch_bounds__(256)
void cvt_all_kernel(CvtSegs segs) {
    int i = blockIdx.x * 256 + threadIdx.x;
    if (i >= segs.end[7]) return;
    int s = 0;
    #pragma unroll
    for (int k = 0; k < 7; ++k) s += (i >= segs.end[k]) ? 1 : 0;
    int base = (s == 0) ? 0 : segs.end[s - 1];
    int j = i - base;
    float4 v = segs.src[s][j];
    ushort4 o;
    o.x = f2bf(v.x); o.y = f2bf(v.y); o.z = f2bf(v.z); o.w = f2bf(v.w);
    segs.dst[s][j] = o;
}

// ---------------- generic C = A * B^T (bf16 in, fp32 out), 128x128 tile ----------------
// Pipelined: loads for tile k+1 issued before MFMAs on tile k (frags in regs).
template<int ADD>
__global__ __launch_bounds__(256)
void gemm_bt(const unsigned short* __restrict__ A, const unsigned short* __restrict__ B,
             float* __restrict__ C, int M, int N, int K) {
    __shared__ unsigned short As[4096];  // [kc=4][m=128][8] bf16
    __shared__ unsigned short Bs[4096];  // [kc=4][n=128][8]
    const int tid  = threadIdx.x;
    const int lane = tid & 63;
    const int wave = tid >> 6;
    const int tm = blockIdx.x * 128;
    const int tn = blockIdx.y * 128;
    const int wm = (wave & 1) * 64;
    const int wn = (wave >> 1) * 64;
    const int quad = lane >> 4;
    const int tr   = lane & 15;

    f32x4 acc[4][4] = {};
    bf16x8 af[4], bfr[4];

    const int ua0 = tid,        am0 = ua0 & 127, ak0 = ua0 >> 7;
    const int ua1 = tid + 256,  am1 = ua1 & 127, ak1 = ua1 >> 7;

    auto issue = [&](int kt) {
        gld_lds16(A + (size_t)(tm + am0) * K + kt + ak0 * 8, &As[ua0 * 8]);
        gld_lds16(A + (size_t)(tm + am1) * K + kt + ak1 * 8, &As[ua1 * 8]);
        gld_lds16(B + (size_t)(tn + am0) * K + kt + ak0 * 8, &Bs[ua0 * 8]);
        gld_lds16(B + (size_t)(tn + am1) * K + kt + ak1 * 8, &Bs[ua1 * 8]);
    };
    auto rdfrags = [&]() {
        #pragma unroll
        for (int mi = 0; mi < 4; ++mi)
            af[mi] = *(const bf16x8*)&As[(quad * 128 + wm + mi * 16 + tr) * 8];
        #pragma unroll
        for (int ni = 0; ni < 4; ++ni)
            bfr[ni] = *(const bf16x8*)&Bs[(quad * 128 + wn + ni * 16 + tr) * 8];
    };
    auto mfmas = [&]() {
        #pragma unroll
        for (int mi = 0; mi < 4; ++mi)
            #pragma unroll
            for (int ni = 0; ni < 4; ++ni)
                acc[mi][ni] = __builtin_amdgcn_mfma_f32_16x16x32_bf16(af[mi], bfr[ni], acc[mi][ni], 0, 0, 0);
    };

    issue(0);
    asm volatile("s_waitcnt vmcnt(0)" ::: "memory");
    __syncthreads();
    rdfrags();
    for (int kt = 32; kt < K; kt += 32) {
        __syncthreads();           // all waves done reading frags of tile k-1
        issue(kt);                 // loads fly while we compute
        mfmas();
        asm volatile("s_waitcnt vmcnt(0)" ::: "memory");
        __syncthreads();
        rdfrags();
    }
    mfmas();

    #pragma unroll
    for (int mi = 0; mi < 4; ++mi) {
        #pragma unroll
        for (int ni = 0; ni < 4; ++ni) {
            int col = tn + wn + ni * 16 + tr;
            #pragma unroll
            for (int r = 0; r < 4; ++r) {
                int row = tm + wm + mi * 16 + quad * 4 + r;
                size_t o = (size_t)row * N + col;
                float v = acc[mi][ni][r];
                if (ADD) v += C[o];
                C[o] = v;
            }
        }
    }
}

// ---------------- fused GEMM1: h = silu(x @ Wg^T) * (x @ Wu^T), bf16 out ----------------
// tile 128(M) x 64(N) dual-B, BK=32, pipelined (round-1 footprint: 16KB LDS)
__global__ __launch_bounds__(256)
void gemm1_swiglu(const unsigned short* __restrict__ Xb, const unsigned short* __restrict__ Wg,
                  const unsigned short* __restrict__ Wu, unsigned short* __restrict__ Hb) {
    const int K = HDIM, N = IDIM;
    __shared__ unsigned short As[4096];  // [4][128][8]
    __shared__ unsigned short Bg[2048];  // [4][64][8]
    __shared__ unsigned short Bu[2048];
    const int tid  = threadIdx.x;
    const int lane = tid & 63;
    const int wave = tid >> 6;
    const int tm = blockIdx.x * 128;
    const int tn = blockIdx.y * 64;
    const int wm = (wave & 1) * 64;
    const int wn = (wave >> 1) * 32;
    const int quad = lane >> 4;
    const int tr   = lane & 15;

    f32x4 ag[4][2] = {};
    f32x4 au[4][2] = {};
    bf16x8 af[4], bg[2], bu[2];

    const int ua0 = tid,       am0 = ua0 & 127, ak0 = ua0 >> 7;
    const int ua1 = tid + 256, am1 = ua1 & 127, ak1 = ua1 >> 7;

    auto issue = [&](int kt) {
        gld_lds16(Xb + (size_t)(tm + am0) * K + kt + ak0 * 8, &As[ua0 * 8]);
        gld_lds16(Xb + (size_t)(tm + am1) * K + kt + ak1 * 8, &As[ua1 * 8]);
        gld_lds16(Wg + (size_t)(tn + lane) * K + kt + wave * 8, &Bg[tid * 8]);
        gld_lds16(Wu + (size_t)(tn + lane) * K + kt + wave * 8, &Bu[tid * 8]);
    };
    auto rdfrags = [&]() {
        #pragma unroll
        for (int mi = 0; mi < 4; ++mi)
            af[mi] = *(const bf16x8*)&As[(quad * 128 + wm + mi * 16 + tr) * 8];
        #pragma unroll
        for (int ni = 0; ni < 2; ++ni) {
            bg[ni] = *(const bf16x8*)&Bg[(quad * 64 + wn + ni * 16 + tr) * 8];
            bu[ni] = *(const bf16x8*)&Bu[(quad * 64 + wn + ni * 16 + tr) * 8];
        }
    };
    auto mfmas = [&]() {
        #pragma unroll
        for (int mi = 0; mi < 4; ++mi)
            #pragma unroll
            for (int ni = 0; ni < 2; ++ni) {
                ag[mi][ni] = __builtin_amdgcn_mfma_f32_16x16x32_bf16(af[mi], bg[ni], ag[mi][ni], 0, 0, 0);
                au[mi][ni] = __builtin_amdgcn_mfma_f32_16x16x32_bf16(af[mi], bu[ni], au[mi][ni], 0, 0, 0);
            }
    };

    issue(0);
    asm volatile("s_waitcnt vmcnt(0)" ::: "memory");
    __syncthreads();
    rdfrags();
    for (int kt = 32; kt < K; kt += 32) {
        __syncthreads();
        issue(kt);
        mfmas();
        asm volatile("s_waitcnt vmcnt(0)" ::: "memory");
        __syncthreads();
        rdfrags();
    }
    mfmas();

    #pragma unroll
    for (int mi = 0; mi < 4; ++mi) {
        #pragma unroll
        for (int ni = 0; ni < 2; ++ni) {
            int col = tn + wn + ni * 16 + tr;
            #pragma unroll
            for (int r = 0; r < 4; ++r) {
                int row = tm + wm + mi * 16 + quad * 4 + r;
                float g = ag[mi][ni][r];
                float u = au[mi][ni][r];
                float h = g / (1.0f + __expf(-g)) * u;  // silu(g)*u
                Hb[(size_t)row * N + col] = f2bf(h);
            }
        }
    }
}

// ---------------- batchnorm stats ----------------
__global__ void bn_stats(const float* __restrict__ gxy, float* __restrict__ sums, float* __restrict__ ssq) {
    const int j = threadIdx.x;
    const int b = blockIdx.x;
    float s = 0.f, q = 0.f;
    for (int r = 0; r < 32; ++r) {
        float v = gxy[(size_t)(b * 32 + r) * 256 + j];
        s += v; q += v * v;
    }
    atomicAdd(&sums[j], s);
    atomicAdd(&ssq[j], q);
}

// ---------------- routing: bn -> log_softmax -> top16 via candidate reduction ----------------
__global__ __launch_bounds__(256)
void routing_kernel(const float* __restrict__ gxy, const float* __restrict__ sums,
                    const float* __restrict__ ssq, int* __restrict__ oidx, float* __restrict__ owt) {
    const int lane = threadIdx.x & 63;
    const int t = blockIdx.x * 4 + (threadIdx.x >> 6);
    const float invT = 1.0f / (float)T_TOK;
    const float* g = gxy + (size_t)t * 256;

    float z[4];
    const int cols[4] = {lane, lane + 64, 128 + lane, 192 + lane};
    #pragma unroll
    for (int i = 0; i < 4; ++i) {
        int c = cols[i];
        float mu  = sums[c] * invT;
        float var = ssq[c] * invT - mu * mu;
        z[i] = (g[c] - mu) * rsqrtf(var + 1e-5f);
    }
    float mx = fmaxf(z[0], z[1]);
    float my = fmaxf(z[2], z[3]);
    #pragma unroll
    for (int m = 32; m >= 1; m >>= 1) {
        mx = fmaxf(mx, __shfl_xor(mx, m));
        my = fmaxf(my, __shfl_xor(my, m));
    }
    float sx = __expf(z[0] - mx) + __expf(z[1] - mx);
    float sy = __expf(z[2] - my) + __expf(z[3] - my);
    #pragma unroll
    for (int m = 32; m >= 1; m >>= 1) {
        sx += __shfl_xor(sx, m);
        sy += __shfl_xor(sy, m);
    }
    float lx0 = z[0] - (mx + __logf(sx)), lx1 = z[1] - (mx + __logf(sx));
    float ly0 = z[2] - (my + __logf(sy)), ly1 = z[3] - (my + __logf(sy));

    float aw = -INFINITY; int ai = 0;
    float bw = -INFINITY; int bi = 0;
    {
        float v0 = lx0, v1 = lx1;
        for (int i = 0; i < 16; ++i) {
            float v; int c;
            if (v0 >= v1) { v = v0; c = lane; } else { v = v1; c = lane + 64; }
            #pragma unroll
            for (int m = 32; m >= 1; m >>= 1) {
                float ov = __shfl_xor(v, m); int oc = __shfl_xor(c, m);
                if (ov > v || (ov == v && oc < c)) { v = ov; c = oc; }
            }
            if ((c & 63) == lane) { if (c < 64) v0 = -INFINITY; else v1 = -INFINITY; }
            if (lane == i) { aw = v; ai = c; }
        }
    }
    {
        float v0 = ly0, v1 = ly1;
        for (int i = 0; i < 16; ++i) {
            float v; int c;
            if (v0 >= v1) { v = v0; c = lane; } else { v = v1; c = lane + 64; }
            #pragma unroll
            for (int m = 32; m >= 1; m >>= 1) {
                float ov = __shfl_xor(v, m); int oc = __shfl_xor(c, m);
                if (ov > v || (ov == v && oc < c)) { v = ov; c = oc; }
            }
            if ((c & 63) == lane) { if (c < 64) v0 = -INFINITY; else v1 = -INFINITY; }
            if (lane == i) { bw = v; bi = c; }
        }
    }
    float cv[4];
    #pragma unroll
    for (int j = 0; j < 4; ++j) {
        int c = lane + 64 * j;
        cv[j] = __shfl(aw, c >> 4) + __shfl(bw, c & 15);
    }
    int myidx = 0; float myw = 0.f;
    for (int i = 0; i < 16; ++i) {
        float v = cv[0]; int c = lane;
        #pragma unroll
        for (int j = 1; j < 4; ++j) { int cc = lane + 64 * j; if (cv[j] > v) { v = cv[j]; c = cc; } }
        #pragma unroll
        for (int m = 32; m >= 1; m >>= 1) {
            float ov = __shfl_xor(v, m); int oc = __shfl_xor(c, m);
            if (ov > v || (ov == v && oc < c)) { v = ov; c = oc; }
        }
        #pragma unroll
        for (int j = 0; j < 4; ++j) if (c == lane + 64 * j) cv[j] = -INFINITY;
        int p = c >> 4, q = c & 15;
        int ex = __shfl(ai, p);
        int ey = __shfl(bi, q);
        if (lane == i) { myidx = ex * 128 + ey; myw = __expf(v); }
    }
    if (lane < 16) {
        oidx[t * TOPK + lane] = myidx;
        owt[t * TOPK + lane]  = myw;
    }
}

// ---------------- expert gather/combine (bf16 tables + bf16 x) ----------------
__global__ __launch_bounds__(256)
void expert_combine(const unsigned short* __restrict__ xb, const int* __restrict__ idx,
                    const float* __restrict__ wts, const unsigned short* __restrict__ ueb,
                    const unsigned short* __restrict__ deb, float* __restrict__ out) {
    const int t = blockIdx.x;
    const int tid = threadIdx.x;
    const int lane = tid & 63, wv = tid >> 6;
    __shared__ float part[TOPK * 4];
    __shared__ float sc[TOPK];
    ushort4 xv4 = ((const ushort4*)(xb + (size_t)t * HDIM))[tid];
    float x0 = bf2f(xv4.x), x1 = bf2f(xv4.y), x2 = bf2f(xv4.z), x3 = bf2f(xv4.w);
    int e[TOPK];
    #pragma unroll
    for (int k = 0; k < TOPK; ++k) e[k] = idx[t * TOPK + k];
    #pragma unroll
    for (int k = 0; k < TOPK; ++k) {
        ushort4 u4 = ((const ushort4*)(ueb + (size_t)e[k] * HDIM))[tid];
        float p = bf2f(u4.x) * x0 + bf2f(u4.y) * x1 + bf2f(u4.z) * x2 + bf2f(u4.w) * x3;
        #pragma unroll
        for (int m = 32; m >= 1; m >>= 1) p += __shfl_xor(p, m);
        if (lane == 0) part[k * 4 + wv] = p;
    }
    __syncthreads();
    if (tid < TOPK) {
        float s = part[tid * 4] + part[tid * 4 + 1] + part[tid * 4 + 2] + part[tid * 4 + 3];
        sc[tid] = s * wts[t * TOPK + tid];
    }
    __syncthreads();
    float4 acc = {0.f, 0.f, 0.f, 0.f};
    #pragma unroll
    for (int k = 0; k < TOPK; ++k) {
        float s = sc[k];
        ushort4 d4 = ((const ushort4*)(deb + (size_t)e[k] * HDIM))[tid];
        acc.x += s * bf2f(d4.x); acc.y += s * bf2f(d4.y);
        acc.z += s * bf2f(d4.z); acc.w += s * bf2f(d4.w);
    }
    ((float4*)(out + (size_t)t * HDIM))[tid] = acc;
}

extern "C" void kernel_launch(void* const* d_in, const int* in_sizes, int n_in,
                              void* d_out, int out_size, void* d_ws, size_t ws_size,
                              hipStream_t stream) {
    const float* x  = (const float*)d_in[0];
    const float* gw = (const float*)d_in[1];
    const float* uw = (const float*)d_in[2];
    const float* dw = (const float*)d_in[3];
    const float* wx = (const float*)d_in[4];
    const float* wy = (const float*)d_in[5];
    const float* ue = (const float*)d_in[6];
    const float* de = (const float*)d_in[7];
    float* out = (float*)d_out;

    char* ws = (char*)d_ws;
    size_t o = 0;
    auto alloc = [&](size_t bytes) { void* p = ws + o; o += (bytes + 255) & ~(size_t)255; return p; };
    unsigned short* xb    = (unsigned short*)alloc((size_t)T_TOK * HDIM * 2);
    unsigned short* gateb = (unsigned short*)alloc((size_t)IDIM * HDIM * 2);
    unsigned short* upb   = (unsigned short*)alloc((size_t)IDIM * HDIM * 2);
    unsigned short* downb = (unsigned short*)alloc((size_t)HDIM * IDIM * 2);
    unsigned short* wrb   = (unsigned short*)alloc((size_t)256 * HDIM * 2);
    unsigned short* ueb   = (unsigned short*)alloc((size_t)16384 * HDIM * 2);
    unsigned short* deb   = (unsigned short*)alloc((size_t)16384 * HDIM * 2);
    unsigned short* hbuf  = (unsigned short*)alloc((size_t)T_TOK * IDIM * 2);
    float* gxy  = (float*)alloc((size_t)T_TOK * 256 * 4);
    float* sums = (float*)alloc(256 * 4);
    float* ssq  = (float*)alloc(256 * 4);
    int*   idxs = (int*)alloc((size_t)T_TOK * TOPK * 4);
    float* wts  = (float*)alloc((size_t)T_TOK * TOPK * 4);

    // merged converts (8 segments)
    CvtSegs segs;
    const float* srcs[8] = {x, gw, uw, dw, wx, wy, ue, de};
    unsigned short* dsts[8] = {xb, gateb, upb, downb, wrb, wrb + SDIM * HDIM, ueb, deb};
    const int cnt4[8] = {T_TOK * HDIM / 4, IDIM * HDIM / 4, IDIM * HDIM / 4, IDIM * HDIM / 4,
                         SDIM * HDIM / 4, SDIM * HDIM / 4, 16384 * HDIM / 4, 16384 * HDIM / 4};
    int acc = 0;
    for (int i = 0; i < 8; ++i) {
        segs.src[i] = (const float4*)srcs[i];
        segs.dst[i] = (ushort4*)dsts[i];
        acc += cnt4[i];
        segs.end[i] = acc;
    }
    cvt_all_kernel<<<(acc + 255) / 256, 256, 0, stream>>>(segs);

    // router logits: gxy[T,256] = xb @ wrb^T
    hipMemsetAsync(sums, 0, 2 * 256 * 4, stream);  // sums+ssq contiguous
    gemm_bt<0><<<dim3(T_TOK / 128, 256 / 128), 256, 0, stream>>>(xb, wrb, gxy, T_TOK, 256, HDIM);
    bn_stats<<<256, 256, 0, stream>>>(gxy, sums, ssq);
    routing_kernel<<<T_TOK / 4, 256, 0, stream>>>(gxy, sums, ssq, idxs, wts);

    // expert branch writes out fully
    expert_combine<<<T_TOK, 256, 0, stream>>>(xb, idxs, wts, ueb, deb, out);

    // MLP branch
    gemm1_swiglu<<<dim3(T_TOK / 128, IDIM / 64), 256, 0, stream>>>(xb, gateb, upb, hbuf);
    gemm_bt<1><<<dim3(T_TOK / 128, HDIM / 128), 256, 0, stream>>>(hbuf, downb, out, T_TOK, HDIM, IDIM);
}